// Round 5
// baseline (213.084 us; speedup 1.0000x reference)
//
#include <hip/hip_runtime.h>
#include <hip/hip_bf16.h>

// R10: latency attack on attn + prep.
//  attn: double-buffered LDS (Ks/Vs[2]) with ONE barrier per k-tile:
//    sync -> ds_write tile kt+1 (regs loaded a full phase ago, vmcnt satisfied)
//    -> issue loads tile kt+2 -> compute tile kt. Barriers 16->9/block, in-loop
//    vmcnt stall eliminated. 32x32 MFMA core + kperm + softmax diet from R9.
//  prep: K-convert 4096->1024 blocks (4 chunks/thread, loads batched before
//    stores); mask-pack 4096->1024 blocks (16 loads batched before ballots).
//    V/W transpose unchanged (conflicts ~1.6us aggregate, not the bottleneck).
// proj unchanged.

typedef __bf16 bf16;
typedef bf16 bf16x8 __attribute__((ext_vector_type(8)));
typedef bf16 bf16x4 __attribute__((ext_vector_type(4)));
typedef float floatx4 __attribute__((ext_vector_type(4)));
typedef float floatx16 __attribute__((ext_vector_type(16)));
typedef unsigned short ushort8 __attribute__((ext_vector_type(8)));
typedef unsigned long long u64;

#define MFMA32(A, B, C)    __builtin_amdgcn_mfma_f32_16x16x32_bf16((A), (B), (C), 0, 0, 0)
#define MFMA32x32(A, B, C) __builtin_amdgcn_mfma_f32_32x32x16_bf16((A), (B), (C), 0, 0, 0)

namespace {
constexpr int S   = 512;
constexpr int H   = 16;
constexpr int Dh  = 64;
constexpr int D   = 1024;
constexpr int LDT = 72;                          // padded LDS row stride (bf16)
constexpr size_t QN = (size_t)16 * S * H * Dh;   // 8,388,608
constexpr size_t WN = (size_t)D * D;             // 1,048,576
}

__device__ __forceinline__ float fexp2(float x) {
#if defined(__HIP_DEVICE_COMPILE__) && __has_builtin(__builtin_amdgcn_exp2f)
    return __builtin_amdgcn_exp2f(x);
#else
    return exp2f(x);
#endif
}

__device__ __forceinline__ int sbfe1(unsigned bits, int bit) {
    return ((int)(bits << (31 - bit))) >> 31;    // folds to v_bfe_i32
}

// Fused prep, grid 4352:
// [0,1024) K f32->bf16 x4 chunks | [1024,3072) V transpose | [3072,3328) W
// transpose | [3328,4352) mask bit-pack x4 units.
__global__ __launch_bounds__(256)
void prep_kernel(const float* __restrict__ Kf, const float* __restrict__ Vf,
                 const float* __restrict__ Wf, const int* __restrict__ Mg,
                 bf16* __restrict__ Kc, bf16* __restrict__ Vt,
                 bf16* __restrict__ Wt, u64* __restrict__ MB)
{
    __shared__ bf16 Ts[64 * LDT];
    const int blk = blockIdx.x, tid = threadIdx.x;

    if (blk < 1024) {                       // ---- K convert, 4 chunks/thread ----
        const int c0 = blk * 1024 + tid;    // chunk ids c0 + 256*k
        floatx4 f[4][2];
#pragma unroll
        for (int k = 0; k < 4; ++k) {
            const float* fs = Kf + (size_t)(c0 + k * 256) * 8;
            f[k][0] = *(const floatx4*)fs;
            f[k][1] = *(const floatx4*)(fs + 4);
        }
#pragma unroll
        for (int k = 0; k < 4; ++k) {
            bf16x8 v;
#pragma unroll
            for (int j = 0; j < 4; ++j) {
                v[j]     = (bf16)f[k][0][j];
                v[j + 4] = (bf16)f[k][1][j];
            }
            *(bf16x8*)(Kc + (size_t)(c0 + k * 256) * 8) = v;
        }
    } else if (blk < 3072) {                // ---- V [b][s][h][d] -> [(bh)][d][s] ----
        const int bk2 = blk - 1024;
        const int bh  = bk2 >> 3, st = bk2 & 7;
        const int b   = bh >> 4, h = bh & 15;
        const int r   = tid >> 2, c = (tid & 3) * 16;
        const float* src = Vf + ((size_t)((b * S + st * 64 + r) * H + h)) * Dh + c;
#pragma unroll
        for (int i = 0; i < 16; ++i)
            Ts[(c + i) * LDT + r] = (bf16)src[i];
        __syncthreads();
        bf16* dst = Vt + ((size_t)bh * 64 + r) * S + st * 64 + c;
        *(ushort8*)dst       = *(const ushort8*)&Ts[r * LDT + c];
        *(ushort8*)(dst + 8) = *(const ushort8*)&Ts[r * LDT + c + 8];
    } else if (blk < 3328) {                // ---- W [k][n] -> [n][k] ----
        const int bk2 = blk - 3072;
        const int nb  = bk2 & 15, kb = bk2 >> 4;
        const int r   = tid >> 2, c = (tid & 3) * 16;
        const float* src = Wf + (size_t)(kb * 64 + r) * D + nb * 64 + c;
#pragma unroll
        for (int i = 0; i < 16; ++i)
            Ts[(c + i) * LDT + r] = (bf16)src[i];
        __syncthreads();
        bf16* dst = Wt + (size_t)(nb * 64 + r) * D + kb * 64 + c;
        *(ushort8*)dst       = *(const ushort8*)&Ts[r * LDT + c];
        *(ushort8*)(dst + 8) = *(const ushort8*)&Ts[r * LDT + c + 8];
    } else {                                // ---- mask -> u64 bitmask, 4 units/wave ----
        const int bk2  = blk - 3328;        // [0,1024)
        const int lane = tid & 63;
        const int wv   = tid >> 6;
        const int u0   = bk2 * 16 + wv * 4; // idx4 base
        int mv[4][4];
#pragma unroll
        for (int u = 0; u < 4; ++u) {
            const int idx4 = u0 + u;
            const int row = idx4 >> 1, hf = idx4 & 1;
#pragma unroll
            for (int r = 0; r < 4; ++r)
                mv[u][r] = Mg[(size_t)row * 512 + hf * 256 + r * 64 + lane];
        }
#pragma unroll
        for (int u = 0; u < 4; ++u) {
            const int idx4 = u0 + u;
            const int row = idx4 >> 1, hf = idx4 & 1;
#pragma unroll
            for (int r = 0; r < 4; ++r) {
                u64 bm = __ballot(mv[u][r] != 0);
                if (lane == 0) MB[(size_t)row * 8 + hf * 4 + r] = bm;
            }
        }
    }
}

// One workgroup = one (b, h, 128-row q-tile). 4 waves x 32 q each (q = qw + l31).
// Double-buffered LDS, one barrier per k-tile.
__global__ __launch_bounds__(256, 4)
void attn_kernel(const float* __restrict__ Qg, const bf16* __restrict__ Kc,
                 const bf16* __restrict__ Vtg, const u64* __restrict__ MB,
                 bf16* __restrict__ heads)
{
    __shared__ bf16 Ks[2][64 * LDT];              // rows PERMUTED: slot r = k-row swap23(r)
    __shared__ bf16 Vs[2][64 * LDT];              // [d][s-in-tile], natural order

    const int tid  = threadIdx.x;
    const int lane = tid & 63;
    const int wave = tid >> 6;
    const int l31  = lane & 31;
    const int half = lane >> 5;

    const int blk = blockIdx.x;                   // ((b*4)+qt)*16 + h
    const int h   = blk & 15;
    const int qt  = (blk >> 4) & 3;
    const int b   = blk >> 6;
    const int qw  = qt * 128 + wave * 32;         // wave's q base; q = qw + l31

    // ---- Q B-frags: lane holds Q[qw+l31][ds*16 + half*8 + j] * 0.125*log2e ----
    constexpr float QSCL = 0.125f * 1.44269504088896340736f;
    bf16x8 aq[4];
    {
        const float* qb = Qg + ((size_t)((b * S + qw + l31) * H + h)) * Dh + half * 8;
#pragma unroll
        for (int ds = 0; ds < 4; ++ds) {
            floatx4 f0 = *(const floatx4*)(qb + ds * 16);
            floatx4 f1 = *(const floatx4*)(qb + ds * 16 + 4);
#pragma unroll
            for (int j = 0; j < 4; ++j) {
                aq[ds][j]     = (bf16)(f0[j] * QSCL);
                aq[ds][j + 4] = (bf16)(f1[j] * QSCL);
            }
        }
    }

    float rsum = 0.f;
    floatx16 O[2];                                // O^T[d = dt*32 + crow][q = l31]
#pragma unroll
    for (int dt = 0; dt < 2; ++dt)
#pragma unroll
        for (int i = 0; i < 16; ++i) O[dt][i] = 0.f;

    const u64* mbrow = MB + ((size_t)b * S + qw + l31) * 8;   // per-lane q row
    const bf16* vplane = Vtg + (size_t)(b * 16 + h) * 64 * S;

    const int sr = tid >> 2, sc_ = (tid & 3) * 16;            // 64x64 staging
    // swap bits 2<->3: staging slot r holds global k-row kperm so the S^T
    // C-tile lands P^T in 32x32x16 B-operand order.
    const int kperm = (sr & 0x33) | ((sr & 4) << 1) | ((sr & 8) >> 1);

    const bf16* ksrc0 = Kc + ((size_t)((b * S + kperm) * H + h)) * Dh + sc_;
    const bf16* vsrc0 = vplane + (size_t)sr * S + sc_;
    const size_t kstep = (size_t)64 * H * Dh;     // Kc elements per k-tile

    // ---- prologue: stage tile 0 into buf 0, prefetch tile 1 into regs ----
    ushort8 k0 = *(const ushort8*)ksrc0;
    ushort8 k1 = *(const ushort8*)(ksrc0 + 8);
    ushort8 v0 = *(const ushort8*)vsrc0;
    ushort8 v1 = *(const ushort8*)(vsrc0 + 8);
    u64 mcur = mbrow[0];
    *(ushort8*)&Ks[0][sr * LDT + sc_]     = k0;
    *(ushort8*)&Ks[0][sr * LDT + sc_ + 8] = k1;
    *(ushort8*)&Vs[0][sr * LDT + sc_]     = v0;
    *(ushort8*)&Vs[0][sr * LDT + sc_ + 8] = v1;
    k0 = *(const ushort8*)(ksrc0 + kstep);
    k1 = *(const ushort8*)(ksrc0 + kstep + 8);
    v0 = *(const ushort8*)(vsrc0 + 64);
    v1 = *(const ushort8*)(vsrc0 + 64 + 8);
    u64 mnext = mbrow[1];

    int p = 0;
    for (int kt = 0; kt < 8; ++kt) {
        __syncthreads();                          // buf[p] visible; buf[p^1] readers done
        if (kt < 7) {                             // ds_write tile kt+1 (vmcnt long satisfied)
            *(ushort8*)&Ks[p ^ 1][sr * LDT + sc_]     = k0;
            *(ushort8*)&Ks[p ^ 1][sr * LDT + sc_ + 8] = k1;
            *(ushort8*)&Vs[p ^ 1][sr * LDT + sc_]     = v0;
            *(ushort8*)&Vs[p ^ 1][sr * LDT + sc_ + 8] = v1;
        }
        const u64 mk = mcur;
        mcur = mnext;
        if (kt < 6) {                             // issue loads tile kt+2; hide under compute
            const bf16* ks = ksrc0 + (size_t)(kt + 2) * kstep;
            const bf16* vs = vsrc0 + (kt + 2) * 64;
            k0 = *(const ushort8*)ks;
            k1 = *(const ushort8*)(ks + 8);
            v0 = *(const ushort8*)vs;
            v1 = *(const ushort8*)(vs + 8);
            mnext = mbrow[kt + 2];
        }

        const bf16* __restrict__ ksp = Ks[p];
        const bf16* __restrict__ vsp = Vs[p];

        // ---- S^T per 32-k tile t: C reg r holds k = t*32 + (r>>3)*16 + half*8 + (r&7) ----
        bf16x8 pB[4];                             // P^T B-operands, 16-k slice each
#pragma unroll
        for (int t = 0; t < 2; ++t) {
            floatx16 acc;
#pragma unroll
            for (int i = 0; i < 16; ++i) acc[i] = 0.f;
#pragma unroll
            for (int ds = 0; ds < 4; ++ds) {
                bf16x8 ak = *(const bf16x8*)&ksp[(t * 32 + l31) * LDT + ds * 16 + half * 8];
                acc = MFMA32x32(ak, aq[ds], acc);
            }
            const unsigned w = (unsigned)(mk >> (t * 32 + half * 8));
#pragma unroll
            for (int r = 0; r < 16; ++r) {
                float e = fexp2(acc[r]);                    // v_exp_f32
                int sx = sbfe1(w, (r >> 3) * 16 + (r & 7)); // 0 or -1
                float pv = __uint_as_float(__float_as_uint(e) & (unsigned)sx);
                rsum += pv;
                pB[t * 2 + (r >> 3)][r & 7] = (bf16)pv;
            }
        }

        // ---- O^T += V^T · P^T ----
#pragma unroll
        for (int dt = 0; dt < 2; ++dt)
#pragma unroll
            for (int s_ = 0; s_ < 4; ++s_) {
                bf16x8 av = *(const bf16x8*)&vsp[(dt * 32 + l31) * LDT + s_ * 16 + half * 8];
                O[dt] = MFMA32x32(av, pB[s_], O[dt]);
            }
        p ^= 1;
    }

    // ---- reduce row sums: lanes l and l+32 share q = l31, disjoint k halves ----
    rsum += __shfl_xor(rsum, 32, 64);
    const float inv = (rsum > 0.f) ? (1.f / rsum) : 0.f;

    // ---- epilogue: O^T[d][q] -> heads[b][q][h][d]; d = dt*32 + g*8 + half*4 + j ----
    bf16* hrow = heads + ((size_t)((b * S + qw + l31) * H + h)) * Dh;
#pragma unroll
    for (int dt = 0; dt < 2; ++dt) {
#pragma unroll
        for (int g = 0; g < 4; ++g) {
            bf16x4 h4;
#pragma unroll
            for (int j = 0; j < 4; ++j) h4[j] = (bf16)(O[dt][g * 4 + j] * inv);
            *(bf16x4*)&hrow[dt * 32 + g * 8 + half * 4] = h4;
        }
    }
}

// Projection: heads (8192x1024) @ Wt^T, 128x128 block tile, 4 waves x 64x64.
__global__ __launch_bounds__(256)
void proj_kernel(const bf16* __restrict__ A, const bf16* __restrict__ Wt,
                 float* __restrict__ out)
{
    __shared__ bf16 As[128 * LDT];
    __shared__ bf16 Ws[128 * LDT];

    const int tid  = threadIdx.x;
    const int lane = tid & 63;
    const int wave = tid >> 6;
    const int l15  = lane & 15;
    const int quad = lane >> 4;

    const int nb = blockIdx.x & 7;
    const int mb = blockIdx.x >> 3;
    const int mbase = mb * 128, nbase = nb * 128;
    const int wm = (wave & 1) * 64, wn = (wave >> 1) * 64;

    const int pr = tid >> 1, pc = (tid & 1) * 32;

    floatx4 O[4][4];
#pragma unroll
    for (int mt = 0; mt < 4; ++mt)
#pragma unroll
        for (int nt = 0; nt < 4; ++nt) O[mt][nt] = floatx4{0.f, 0.f, 0.f, 0.f};

    for (int kt = 0; kt < 16; ++kt) {
        const int kb = kt * 64;
        const bf16* asrc = A  + (size_t)(mbase + pr) * D + kb + pc;
        const bf16* wsrc = Wt + (size_t)(nbase + pr) * D + kb + pc;
        ushort8 a0 = *(const ushort8*)asrc;
        ushort8 a1 = *(const ushort8*)(asrc + 8);
        ushort8 a2 = *(const ushort8*)(asrc + 16);
        ushort8 a3 = *(const ushort8*)(asrc + 24);
        ushort8 w0 = *(const ushort8*)wsrc;
        ushort8 w1 = *(const ushort8*)(wsrc + 8);
        ushort8 w2 = *(const ushort8*)(wsrc + 16);
        ushort8 w3 = *(const ushort8*)(wsrc + 24);

        __syncthreads();
        *(ushort8*)&As[pr * LDT + pc]      = a0;
        *(ushort8*)&As[pr * LDT + pc + 8]  = a1;
        *(ushort8*)&As[pr * LDT + pc + 16] = a2;
        *(ushort8*)&As[pr * LDT + pc + 24] = a3;
        *(ushort8*)&Ws[pr * LDT + pc]      = w0;
        *(ushort8*)&Ws[pr * LDT + pc + 8]  = w1;
        *(ushort8*)&Ws[pr * LDT + pc + 16] = w2;
        *(ushort8*)&Ws[pr * LDT + pc + 24] = w3;
        __syncthreads();

        bf16x8 fa[4][2];
#pragma unroll
        for (int mt = 0; mt < 4; ++mt) {
            fa[mt][0] = *(const bf16x8*)&As[(wm + mt * 16 + l15) * LDT + quad * 8];
            fa[mt][1] = *(const bf16x8*)&As[(wm + mt * 16 + l15) * LDT + quad * 8 + 32];
        }
#pragma unroll
        for (int nt = 0; nt < 4; ++nt) {
            bf16x8 fb0 = *(const bf16x8*)&Ws[(wn + nt * 16 + l15) * LDT + quad * 8];
            bf16x8 fb1 = *(const bf16x8*)&Ws[(wn + nt * 16 + l15) * LDT + quad * 8 + 32];
#pragma unroll
            for (int mt = 0; mt < 4; ++mt) {
                O[mt][nt] = MFMA32(fa[mt][0], fb0, O[mt][nt]);
                O[mt][nt] = MFMA32(fa[mt][1], fb1, O[mt][nt]);
            }
        }
    }

#pragma unroll
    for (int mt = 0; mt < 4; ++mt) {
#pragma unroll
        for (int nt = 0; nt < 4; ++nt) {
#pragma unroll
            for (int reg = 0; reg < 4; ++reg) {
                const int m = mbase + wm + mt * 16 + quad * 4 + reg;
                const int n = nbase + wn + nt * 16 + l15;
                out[(size_t)m * D + n] = O[mt][nt][reg];
            }
        }
    }
}

extern "C" void kernel_launch(void* const* d_in, const int* in_sizes, int n_in,
                              void* d_out, int out_size, void* d_ws, size_t ws_size,
                              hipStream_t stream)
{
    const float* pre_q = (const float*)d_in[0];
    const float* pre_v = (const float*)d_in[1];
    const float* pre_k = (const float*)d_in[2];
    const int*   mask  = (const int*)d_in[3];
    const float* Wg    = (const float*)d_in[4];
    float* out = (float*)d_out;

    bf16* Kc    = (bf16*)d_ws;
    bf16* Vt    = Kc + QN;
    bf16* Wt    = Vt + QN;
    bf16* heads = Wt + WN;
    u64*  MB    = (u64*)(heads + QN);

    prep_kernel<<<4352, 256, 0, stream>>>(pre_k, pre_v, Wg, mask, Kc, Vt, Wt, MB);
    attn_kernel<<<1024, 256, 0, stream>>>(pre_q, Kc, Vt, MB, heads);
    proj_kernel<<<512, 256, 0, stream>>>(heads, Wt, out);
}

// Round 6
// 209.378 us; speedup vs baseline: 1.0177x; 1.0177x over previous
//
#include <hip/hip_runtime.h>
#include <hip/hip_bf16.h>

// R11:
//  attn: exact R9 form (single-buffer, 32x32 MFMA, kperm, softmax diet) --
//    R7/R10 both falsified the register-pipeline family (spill traffic).
//  proj: m97 structure (guide 5: 128^2 tile, BK=32, LINEAR LDS,
//    global_load_lds width=16, 2 barriers/K-step). Removes reg-staging
//    VALU/latency cost; ladder-measured 517->874 TF for this exact change.
//  prep: V/W transpose LDS write swizzle (col ^= row&48): write bank
//    conflicts 8-way -> 2-way; read side unchanged (XOR commutes with the
//    contiguous 16B-aligned read runs).

typedef __bf16 bf16;
typedef bf16 bf16x8 __attribute__((ext_vector_type(8)));
typedef bf16 bf16x4 __attribute__((ext_vector_type(4)));
typedef float floatx4 __attribute__((ext_vector_type(4)));
typedef float floatx16 __attribute__((ext_vector_type(16)));
typedef unsigned short ushort8 __attribute__((ext_vector_type(8)));
typedef unsigned long long u64;

#define MFMA32(A, B, C)    __builtin_amdgcn_mfma_f32_16x16x32_bf16((A), (B), (C), 0, 0, 0)
#define MFMA32x32(A, B, C) __builtin_amdgcn_mfma_f32_32x32x16_bf16((A), (B), (C), 0, 0, 0)

namespace {
constexpr int S   = 512;
constexpr int H   = 16;
constexpr int Dh  = 64;
constexpr int D   = 1024;
constexpr int LDT = 72;                          // padded LDS row stride (bf16)
constexpr size_t QN = (size_t)16 * S * H * Dh;   // 8,388,608
constexpr size_t WN = (size_t)D * D;             // 1,048,576
}

__device__ __forceinline__ float fexp2(float x) {
#if defined(__HIP_DEVICE_COMPILE__) && __has_builtin(__builtin_amdgcn_exp2f)
    return __builtin_amdgcn_exp2f(x);
#else
    return exp2f(x);
#endif
}

__device__ __forceinline__ int sbfe1(unsigned bits, int bit) {
    return ((int)(bits << (31 - bit))) >> 31;    // folds to v_bfe_i32
}

// Async global->LDS, 16B per lane. lds base must be wave-uniform (HW adds lane*16).
__device__ __forceinline__ void gload16(const bf16* g, bf16* ldsbase, int lane) {
#if __has_builtin(__builtin_amdgcn_global_load_lds)
    __builtin_amdgcn_global_load_lds(
        (__attribute__((address_space(1))) void*)(g),
        (__attribute__((address_space(3))) void*)(ldsbase), 16, 0, 0);
#else
    *(ushort8*)(ldsbase + lane * 8) = *(const ushort8*)g;   // host-pass / fallback
#endif
}

// Fused prep, grid 4352:
// [0,1024) K f32->bf16 x4 chunks | [1024,3072) V transpose | [3072,3328) W
// transpose | [3328,4352) mask bit-pack x4 units.
__global__ __launch_bounds__(256)
void prep_kernel(const float* __restrict__ Kf, const float* __restrict__ Vf,
                 const float* __restrict__ Wf, const int* __restrict__ Mg,
                 bf16* __restrict__ Kc, bf16* __restrict__ Vt,
                 bf16* __restrict__ Wt, u64* __restrict__ MB)
{
    __shared__ bf16 Ts[64 * LDT];
    const int blk = blockIdx.x, tid = threadIdx.x;

    if (blk < 1024) {                       // ---- K convert, 4 chunks/thread ----
        const int c0 = blk * 1024 + tid;    // chunk ids c0 + 256*k
        floatx4 f[4][2];
#pragma unroll
        for (int k = 0; k < 4; ++k) {
            const float* fs = Kf + (size_t)(c0 + k * 256) * 8;
            f[k][0] = *(const floatx4*)fs;
            f[k][1] = *(const floatx4*)(fs + 4);
        }
#pragma unroll
        for (int k = 0; k < 4; ++k) {
            bf16x8 v;
#pragma unroll
            for (int j = 0; j < 4; ++j) {
                v[j]     = (bf16)f[k][0][j];
                v[j + 4] = (bf16)f[k][1][j];
            }
            *(bf16x8*)(Kc + (size_t)(c0 + k * 256) * 8) = v;
        }
    } else if (blk < 3072) {                // ---- V [b][s][h][d] -> [(bh)][d][s] ----
        const int bk2 = blk - 1024;
        const int bh  = bk2 >> 3, st = bk2 & 7;
        const int b   = bh >> 4, h = bh & 15;
        const int r   = tid >> 2, c = (tid & 3) * 16;
        const float* src = Vf + ((size_t)((b * S + st * 64 + r) * H + h)) * Dh + c;
        // element (d,s) stored at d*LDT + (s ^ (d&48)): write conflicts 8->2-way
#pragma unroll
        for (int i = 0; i < 16; ++i)
            Ts[(c + i) * LDT + (r ^ ((c + i) & 48))] = (bf16)src[i];
        __syncthreads();
        bf16* dst = Vt + ((size_t)bh * 64 + r) * S + st * 64 + c;
        const int rb = r * LDT + (c ^ (r & 48));
        *(ushort8*)dst       = *(const ushort8*)&Ts[rb];
        *(ushort8*)(dst + 8) = *(const ushort8*)&Ts[rb + 8];
    } else if (blk < 3328) {                // ---- W [k][n] -> [n][k] ----
        const int bk2 = blk - 3072;
        const int nb  = bk2 & 15, kb = bk2 >> 4;
        const int r   = tid >> 2, c = (tid & 3) * 16;
        const float* src = Wf + (size_t)(kb * 64 + r) * D + nb * 64 + c;
#pragma unroll
        for (int i = 0; i < 16; ++i)
            Ts[(c + i) * LDT + (r ^ ((c + i) & 48))] = (bf16)src[i];
        __syncthreads();
        bf16* dst = Wt + (size_t)(nb * 64 + r) * D + kb * 64 + c;
        const int rb = r * LDT + (c ^ (r & 48));
        *(ushort8*)dst       = *(const ushort8*)&Ts[rb];
        *(ushort8*)(dst + 8) = *(const ushort8*)&Ts[rb + 8];
    } else {                                // ---- mask -> u64 bitmask, 4 units/wave ----
        const int bk2  = blk - 3328;        // [0,1024)
        const int lane = tid & 63;
        const int wv   = tid >> 6;
        const int u0   = bk2 * 16 + wv * 4; // idx4 base
        int mv[4][4];
#pragma unroll
        for (int u = 0; u < 4; ++u) {
            const int idx4 = u0 + u;
            const int row = idx4 >> 1, hf = idx4 & 1;
#pragma unroll
            for (int r = 0; r < 4; ++r)
                mv[u][r] = Mg[(size_t)row * 512 + hf * 256 + r * 64 + lane];
        }
#pragma unroll
        for (int u = 0; u < 4; ++u) {
            const int idx4 = u0 + u;
            const int row = idx4 >> 1, hf = idx4 & 1;
#pragma unroll
            for (int r = 0; r < 4; ++r) {
                u64 bm = __ballot(mv[u][r] != 0);
                if (lane == 0) MB[(size_t)row * 8 + hf * 4 + r] = bm;
            }
        }
    }
}

// One workgroup = one (b, h, 128-row q-tile). 4 waves x 32 q each (q = qw + l31).
// S^T and PV on mfma_f32_32x32x16_bf16; C/D: col=lane&31, row=(reg&3)+8*(reg>>2)+4*half.
__global__ __launch_bounds__(256, 4)
void attn_kernel(const float* __restrict__ Qg, const bf16* __restrict__ Kc,
                 const bf16* __restrict__ Vtg, const u64* __restrict__ MB,
                 bf16* __restrict__ heads)
{
    __shared__ bf16 Ks[64 * LDT];                 // rows PERMUTED: slot r = k-row swap23(r)
    __shared__ bf16 Vt[64 * LDT];                 // [d][s-in-tile], natural order

    const int tid  = threadIdx.x;
    const int lane = tid & 63;
    const int wave = tid >> 6;
    const int l31  = lane & 31;
    const int half = lane >> 5;

    const int blk = blockIdx.x;                   // ((b*4)+qt)*16 + h
    const int h   = blk & 15;
    const int qt  = (blk >> 4) & 3;
    const int b   = blk >> 6;
    const int qw  = qt * 128 + wave * 32;         // wave's q base; q = qw + l31

    // ---- Q B-frags: lane holds Q[qw+l31][ds*16 + half*8 + j] * 0.125*log2e ----
    constexpr float QSCL = 0.125f * 1.44269504088896340736f;
    bf16x8 aq[4];
    {
        const float* qb = Qg + ((size_t)((b * S + qw + l31) * H + h)) * Dh + half * 8;
#pragma unroll
        for (int ds = 0; ds < 4; ++ds) {
            floatx4 f0 = *(const floatx4*)(qb + ds * 16);
            floatx4 f1 = *(const floatx4*)(qb + ds * 16 + 4);
#pragma unroll
            for (int j = 0; j < 4; ++j) {
                aq[ds][j]     = (bf16)(f0[j] * QSCL);
                aq[ds][j + 4] = (bf16)(f1[j] * QSCL);
            }
        }
    }

    float rsum = 0.f;
    floatx16 O[2];                                // O^T[d = dt*32 + crow][q = l31]
#pragma unroll
    for (int dt = 0; dt < 2; ++dt)
#pragma unroll
        for (int i = 0; i < 16; ++i) O[dt][i] = 0.f;

    const u64* mbrow = MB + ((size_t)b * S + qw + l31) * 8;   // per-lane q row
    const bf16* vplane = Vtg + (size_t)(b * 16 + h) * 64 * S;

    const int sr = tid >> 2, sc_ = (tid & 3) * 16;            // 64x64 staging
    // swap bits 2<->3: staging slot r holds global k-row kperm so the S^T
    // C-tile lands P^T in 32x32x16 B-operand order (slot s*8+j <-> C reg s*8+j).
    const int kperm = (sr & 0x33) | ((sr & 4) << 1) | ((sr & 8) >> 1);

    for (int kt = 0; kt < 8; ++kt) {
        const int kb = kt * 64;
        const bf16* ksrc = Kc + ((size_t)((b * S + kb + kperm) * H + h)) * Dh + sc_;
        const bf16* vsrc = vplane + (size_t)sr * S + kb + sc_;
        ushort8 k0 = *(const ushort8*)ksrc;
        ushort8 k1 = *(const ushort8*)(ksrc + 8);
        ushort8 v0 = *(const ushort8*)vsrc;
        ushort8 v1 = *(const ushort8*)(vsrc + 8);
        u64 m64 = mbrow[kt];                      // bit k of this lane's q row

        __syncthreads();                          // prev tile's LDS reads done
        *(ushort8*)&Ks[sr * LDT + sc_]     = k0;
        *(ushort8*)&Ks[sr * LDT + sc_ + 8] = k1;
        *(ushort8*)&Vt[sr * LDT + sc_]     = v0;
        *(ushort8*)&Vt[sr * LDT + sc_ + 8] = v1;
        __syncthreads();

        // ---- S^T per 32-k tile t: C reg r holds k = t*32 + (r>>3)*16 + half*8 + (r&7) ----
        bf16x8 pB[4];                             // P^T B-operands, 16-k slice each
#pragma unroll
        for (int t = 0; t < 2; ++t) {
            floatx16 acc;
#pragma unroll
            for (int i = 0; i < 16; ++i) acc[i] = 0.f;
#pragma unroll
            for (int ds = 0; ds < 4; ++ds) {
                bf16x8 ak = *(const bf16x8*)&Ks[(t * 32 + l31) * LDT + ds * 16 + half * 8];
                acc = MFMA32x32(ak, aq[ds], acc);
            }
            const unsigned w = (unsigned)(m64 >> (t * 32 + half * 8));
#pragma unroll
            for (int r = 0; r < 16; ++r) {
                float e = fexp2(acc[r]);                    // v_exp_f32
                int sx = sbfe1(w, (r >> 3) * 16 + (r & 7)); // 0 or -1
                float p = __uint_as_float(__float_as_uint(e) & (unsigned)sx);
                rsum += p;
                pB[t * 2 + (r >> 3)][r & 7] = (bf16)p;
            }
        }

        // ---- O^T += V^T · P^T : A = Vt rows (natural), B = pB k-slices ----
#pragma unroll
        for (int dt = 0; dt < 2; ++dt)
#pragma unroll
            for (int s_ = 0; s_ < 4; ++s_) {
                bf16x8 av = *(const bf16x8*)&Vt[(dt * 32 + l31) * LDT + s_ * 16 + half * 8];
                O[dt] = MFMA32x32(av, pB[s_], O[dt]);
            }
    }

    // ---- reduce row sums: lanes l and l+32 share q = l31, disjoint k halves ----
    rsum += __shfl_xor(rsum, 32, 64);
    const float inv = (rsum > 0.f) ? (1.f / rsum) : 0.f;

    // ---- epilogue: O^T[d][q] -> heads[b][q][h][d]; d = dt*32 + g*8 + half*4 + j ----
    bf16* hrow = heads + ((size_t)((b * S + qw + l31) * H + h)) * Dh;
#pragma unroll
    for (int dt = 0; dt < 2; ++dt) {
#pragma unroll
        for (int g = 0; g < 4; ++g) {
            bf16x4 h4;
#pragma unroll
            for (int j = 0; j < 4; ++j) h4[j] = (bf16)(O[dt][g * 4 + j] * inv);
            *(bf16x4*)&hrow[dt * 32 + g * 8 + half * 4] = h4;
        }
    }
}

// Projection: heads (8192x1024) @ Wt^T. m97 structure: 128x128 tile, BK=32,
// LINEAR LDS, global_load_lds width=16, 2 barriers per K-step.
__global__ __launch_bounds__(256)
void proj_kernel(const bf16* __restrict__ A, const bf16* __restrict__ Wt,
                 float* __restrict__ out)
{
    __shared__ bf16 As[128 * 32];                 // linear, 8 KB
    __shared__ bf16 Ws[128 * 32];                 // linear, 8 KB

    const int tid  = threadIdx.x;
    const int lane = tid & 63;
    const int wave = tid >> 6;
    const int l15  = lane & 15;
    const int quad = lane >> 4;

    const int nb = blockIdx.x & 7;
    const int mb = blockIdx.x >> 3;
    const int mbase = mb * 128, nbase = nb * 128;
    const int wm = (wave & 1) * 64, wn = (wave >> 1) * 64;

    // staging: wave handles chunks {2w, 2w+1}; chunk = 16 rows x 32 cols (1 KB)
    const int ch0  = wave * 2;
    const int srow = lane >> 2;                   // 0..15 within chunk
    const int scol = (lane & 3) * 8;              // bf16 col

    floatx4 O[4][4];
#pragma unroll
    for (int mt = 0; mt < 4; ++mt)
#pragma unroll
        for (int nt = 0; nt < 4; ++nt) O[mt][nt] = floatx4{0.f, 0.f, 0.f, 0.f};

    for (int kt = 0; kt < 32; ++kt) {
        const int kb = kt * 32;
        if (kt) __syncthreads();                  // prev compute done; LDS free

        gload16(A  + (size_t)(mbase + ch0 * 16      + srow) * D + kb + scol, As + ch0 * 512,       lane);
        gload16(A  + (size_t)(mbase + (ch0 + 1) * 16 + srow) * D + kb + scol, As + (ch0 + 1) * 512, lane);
        gload16(Wt + (size_t)(nbase + ch0 * 16      + srow) * D + kb + scol, Ws + ch0 * 512,       lane);
        gload16(Wt + (size_t)(nbase + (ch0 + 1) * 16 + srow) * D + kb + scol, Ws + (ch0 + 1) * 512, lane);

        __syncthreads();                          // vmcnt drained -> LDS visible

        bf16x8 fa[4];
#pragma unroll
        for (int mt = 0; mt < 4; ++mt)
            fa[mt] = *(const bf16x8*)&As[(wm + mt * 16 + l15) * 32 + quad * 8];
#pragma unroll
        for (int nt = 0; nt < 4; ++nt) {
            bf16x8 fb = *(const bf16x8*)&Ws[(wn + nt * 16 + l15) * 32 + quad * 8];
#pragma unroll
            for (int mt = 0; mt < 4; ++mt)
                O[mt][nt] = MFMA32(fa[mt], fb, O[mt][nt]);
        }
    }

#pragma unroll
    for (int mt = 0; mt < 4; ++mt) {
#pragma unroll
        for (int nt = 0; nt < 4; ++nt) {
#pragma unroll
            for (int reg = 0; reg < 4; ++reg) {
                const int m = mbase + wm + mt * 16 + quad * 4 + reg;
                const int n = nbase + wn + nt * 16 + l15;
                out[(size_t)m * D + n] = O[mt][nt][reg];
            }
        }
    }
}

extern "C" void kernel_launch(void* const* d_in, const int* in_sizes, int n_in,
                              void* d_out, int out_size, void* d_ws, size_t ws_size,
                              hipStream_t stream)
{
    const float* pre_q = (const float*)d_in[0];
    const float* pre_v = (const float*)d_in[1];
    const float* pre_k = (const float*)d_in[2];
    const int*   mask  = (const int*)d_in[3];
    const float* Wg    = (const float*)d_in[4];
    float* out = (float*)d_out;

    bf16* Kc    = (bf16*)d_ws;
    bf16* Vt    = Kc + QN;
    bf16* Wt    = Vt + QN;
    bf16* heads = Wt + WN;
    u64*  MB    = (u64*)(heads + QN);

    prep_kernel<<<4352, 256, 0, stream>>>(pre_k, pre_v, Wg, mask, Kc, Vt, Wt, MB);
    attn_kernel<<<1024, 256, 0, stream>>>(pre_q, Kc, Vt, MB, heads);
    proj_kernel<<<512, 256, 0, stream>>>(heads, Wt, out);
}